// Round 9
// baseline (261.318 us; speedup 1.0000x reference)
//
#include <hip/hip_runtime.h>
#include <hip/hip_bf16.h>

typedef __attribute__((ext_vector_type(4))) float f32x4;
typedef __attribute__((ext_vector_type(8))) short bf16x8;

#define MFMA16(a, b, c) __builtin_amdgcn_mfma_f32_16x16x32_bf16((a), (b), (c), 0, 0, 0)

// ---- LDS layout (bytes): W1 kb0-5 (128 rows x 24 chunks x 16B = 48K) + params.
// 51744 B < 64 KiB: no dynamic-LDS opt-in attribute needed. Co-residency test:
// every round that requested >64KiB LDS got 1 block/CU at 512 thr (R6-R8);
// this round's LDS fits 2 blocks (103K) or 3 (155K) in 160 KiB.
// W1 kb6-7 (8K) + W2 (16K) stream from global in lane-linear layout (coalesced
// 1KB/wave loads, L1-hot -- fixes R8's 64-lines-per-instr scattered W2 reads).
#define W1T_OFF 0        // 128 rows x 192 shorts (24 chunks), XOR-swizzled in-group
#define B1_OFF  49152
#define G1_OFF  49664
#define E1_OFF  50176
#define B2_OFF  50688
#define G2_OFF  50944
#define E2_OFF  51200
#define W3_OFF  51456
#define B3_OFF  51712
#define SMEM_BYTES 51744

__device__ __forceinline__ short f2bf(float x) {
  __hip_bfloat16 h = __float2bfloat16(x);
  return __builtin_bit_cast(short, h);
}

__device__ __forceinline__ bf16x8 pack8(f32x4 a, f32x4 b) {
  bf16x8 r;
  r[0] = f2bf(a[0]); r[1] = f2bf(a[1]); r[2] = f2bf(a[2]); r[3] = f2bf(a[3]);
  r[4] = f2bf(b[0]); r[5] = f2bf(b[1]); r[6] = f2bf(b[2]); r[7] = f2bf(b[3]);
  return r;
}

// GELU via logistic CDF fit with log2e folded into the polynomial:
// gelu(z) = z * sigmoid(1.5976 z + 0.0705657 z^3)
//         = z / (1 + exp2(z*(c1 + c2 z^2))), c = -coef*log2(e).
// |err| <~ 5e-4, under bf16 matmul noise (R4-R8 passed absmax 0.0078).
__device__ __forceinline__ float gelu_fast(float z) {
  float s = z * z;
  float y = z * __builtin_fmaf(-0.10180479f, s, -2.3048496f);
  float t = __builtin_amdgcn_exp2f(y);
  return z * __builtin_amdgcn_rcpf(1.0f + t);
}

// One-time weight prep into workspace:
//   w1i (24576 sh): W1 chunks 0..23 as the XOR-swizzled LDS image (pos formula
//        identical to R1-R8 for chunk<24 since XOR touches only low 3 bits).
//   w1b (8192 sh): W1 chunks 24..31 (kb 6,7) as lane-linear fragments:
//        [((kb-6)*8+nt)*512 + lane*8 + e], lane = q*16 + (n&15), nt = n>>4.
//   w2L (8192 sh): W2 pi-permuted fragments lane-linear:
//        [(kb2*4+t)*512 + lane*8 + e]; pi verified R2-R8.
__global__ __launch_bounds__(256) void prep_weights(
    const float* __restrict__ W1, const float* __restrict__ W2,
    short* __restrict__ w1i, short* __restrict__ w1b, short* __restrict__ w2L) {
  int idx = blockIdx.x * 256 + threadIdx.x;
  if (idx < 32768) {                       // W1 [k=256][n=128] row-major
    int k = idx >> 7, n = idx & 127;
    int chunk = k >> 3, e = k & 7;
    short v = f2bf(W1[idx]);
    if (chunk < 24) {
      int pos = (chunk & 24) | ((chunk & 7) ^ (n & 7));
      w1i[n * 192 + pos * 8 + e] = v;
    } else {
      int kb = chunk >> 2;                 // 6 or 7
      int qq = chunk & 3;
      int lane = qq * 16 + (n & 15);
      int nt = n >> 4;
      w1b[((kb - 6) * 8 + nt) * 512 + lane * 8 + e] = v;
    }
  } else if (idx < 40960) {                // W2 [n=128][n2=64] row-major
    int j = idx - 32768;
    int n = j >> 6, n2 = j & 63;
    // forward pi: k = (n>>5)*32 + ((n>>2)&3)*8 + ((n>>4)&1)*4 + (n&3)
    int kb2 = n >> 5;
    int qf = (n >> 2) & 3;
    int e = ((n >> 4) & 1) * 4 + (n & 3);
    int t = n2 >> 4, cc2 = n2 & 15;
    w2L[(kb2 * 4 + t) * 512 + (qf * 16 + cc2) * 8 + e] = f2bf(W2[j]);
  }
}

// One-time feature-table conversion f32 -> bf16 (R8-proven: FETCH 307->68 MB).
__global__ __launch_bounds__(256) void prep_feats(
    const float* __restrict__ f, short* __restrict__ o, int n8) {
  int idx = blockIdx.x * 256 + threadIdx.x;
  if (idx < n8) {
    f32x4 a = *(const f32x4*)(f + idx * 8);
    f32x4 b = *(const f32x4*)(f + idx * 8 + 4);
    *(bf16x8*)(o + idx * 8) = pack8(a, b);
  }
}

// Fused gather + (256->128 LN GELU) + (128->64 LN GELU) + (64->1).
// 8 waves/block (512 thr), 16 edges/wave, 128-edge tiles.
// Register lessons (R2-R8, counter-verified): (512,2) = 128-reg budget, no
// spill at ~72-90 regs; 1024-thr = 64-reg budget (always spills this body);
// global loads in epilogues must be fenced (sched_barrier) or params in LDS.
// pi-trick: layer-2 B operand = layer-1 accumulators (no H1 round-trip).
__global__ __launch_bounds__(512, 2) void mlp_fused(
    const short* __restrict__ drugb, const short* __restrict__ disb,
    const int* __restrict__ src, const int* __restrict__ dst,
    const short* __restrict__ w1i, const short* __restrict__ w1b,
    const short* __restrict__ w2L,
    const float* __restrict__ b1, const float* __restrict__ g1, const float* __restrict__ be1,
    const float* __restrict__ b2, const float* __restrict__ g2, const float* __restrict__ be2,
    const float* __restrict__ W3, const float* __restrict__ b3,
    float* __restrict__ out, int E, int ntiles) {
  extern __shared__ char smem[];
  short* w1t = (short*)(smem + W1T_OFF);
  float* b1s = (float*)(smem + B1_OFF);
  float* g1s = (float*)(smem + G1_OFF);
  float* e1s = (float*)(smem + E1_OFF);
  float* b2s = (float*)(smem + B2_OFF);
  float* g2s = (float*)(smem + G2_OFF);
  float* e2s = (float*)(smem + E2_OFF);
  float* w3s = (float*)(smem + W3_OFF);
  float* b3s = (float*)(smem + B3_OFF);

  const int tid  = threadIdx.x;
  const int wave = tid >> 6;    // 0..7
  const int lane = tid & 63;
  const int q    = lane >> 4;   // quad (0..3)
  const int cc   = lane & 15;   // col-within-tile = edge slot

  // ---- one-time: linear copy of pre-swizzled 48KB W1 image into LDS ----
  #pragma unroll
  for (int o = 0; o < 6; ++o) {
    int s = (tid + o * 512) * 8;           // shorts; 16B/thread/pass, 6 passes
    *(bf16x8*)(w1t + s) = *(const bf16x8*)(w1i + s);
  }
  if (tid < 128) { b1s[tid] = b1[tid]; g1s[tid] = g1[tid]; e1s[tid] = be1[tid]; }
  else if (tid < 192) { int j = tid - 128; b2s[j] = b2[j]; g2s[j] = g2[j]; e2s[j] = be2[j]; w3s[j] = W3[j]; }
  if (tid == 256) b3s[0] = b3[0];
  __syncthreads();

  // per-lane global fragment bases (lane-linear, coalesced, L1-hot)
  const short* w1bp = w1b + (lane << 3);
  const short* w2p  = w2L + (lane << 3);

  // ---- persistent loop over 128-edge tiles; waves free-run (no per-tile sync) ----
  for (int tile = blockIdx.x; tile < ntiles; tile += gridDim.x) {
    const int r  = tile * 128 + wave * 16 + cc;       // this lane's edge row
    const int rc = (r < E) ? r : (E - 1);             // clamp reads, guard writes
    const short* pd = drugb + (size_t)src[rc] * 128 + q * 8;
    const short* pq = disb  + (size_t)dst[rc] * 128 + q * 8;

    // ===== layer 1: [256]->[128], K=256, acc init = b1 (bias folded) =====
    f32x4 acc1[8];
    #pragma unroll
    for (int nt = 0; nt < 8; ++nt)
      acc1[nt] = *(const f32x4*)(b1s + nt * 16 + q * 4);

    bf16x8 u = *(const bf16x8*)pd;         // prefetch kb=0
    // kb 0..5: A-fragments from LDS (XOR-swizzled, conflict-free)
    #pragma unroll 1
    for (int kb = 0; kb < 6; ++kb) {
      bf16x8 bfr = u;
      {                                    // issue kb+1 load before kb's MFMAs
        const short* pn = (kb < 3) ? (pd + (kb + 1) * 32) : (pq + (kb - 3) * 32);
        u = *(const bf16x8*)pn;
      }
      const char* abase = (const char*)w1t + cc * 384 + ((((kb * 4 + q) ^ (cc & 7))) << 4);
      #pragma unroll
      for (int nt = 0; nt < 8; ++nt) {
        bf16x8 af = *(const bf16x8*)(abase + nt * 6144);
        acc1[nt] = MFMA16(af, bfr, acc1[nt]);
      }
    }
    // kb 6..7: A-fragments streamed from global (lane-linear, fenced per kb)
    #pragma unroll
    for (int kb = 6; kb < 8; ++kb) {
      bf16x8 bfr = u;
      if (kb < 7) u = *(const bf16x8*)(pq + 96);      // prefetch kb=7 B-operand
      const short* gb = w1bp + (kb - 6) * 4096;
      #pragma unroll
      for (int nt = 0; nt < 8; ++nt) {
        bf16x8 af = *(const bf16x8*)(gb + nt * 512);
        acc1[nt] = MFMA16(af, bfr, acc1[nt]);
      }
      __builtin_amdgcn_sched_barrier(0);   // cap in-flight W1b loads at 8/kb
    }

    // epilogue 1: LN over n=128, GELU, pack to bf16 hreg (acc1 dies here)
    bf16x8 hreg[4];
    {
      float s = 0.f, ss = 0.f;
      #pragma unroll
      for (int nt = 0; nt < 8; ++nt)
        #pragma unroll
        for (int j = 0; j < 4; ++j) { float v = acc1[nt][j]; s += v; ss += v * v; }
      s  += __shfl_xor(s, 16);  s  += __shfl_xor(s, 32);
      ss += __shfl_xor(ss, 16); ss += __shfl_xor(ss, 32);
      float mu   = s * 0.0078125f;
      float var  = ss * 0.0078125f - mu * mu;
      var = (var > 0.f) ? var : 0.f;
      float rstd = __builtin_amdgcn_rsqf(var + 1e-5f);

      #pragma unroll
      for (int h = 0; h < 4; ++h) {
        f32x4 glo = *(const f32x4*)(g1s + (2 * h) * 16 + q * 4);
        f32x4 elo = *(const f32x4*)(e1s + (2 * h) * 16 + q * 4);
        f32x4 ghi = *(const f32x4*)(g1s + (2 * h + 1) * 16 + q * 4);
        f32x4 ehi = *(const f32x4*)(e1s + (2 * h + 1) * 16 + q * 4);
        f32x4 a, b;
        #pragma unroll
        for (int j = 0; j < 4; ++j) {
          a[j] = gelu_fast(__builtin_fmaf((acc1[2 * h][j] - mu) * rstd, glo[j], elo[j]));
          b[j] = gelu_fast(__builtin_fmaf((acc1[2 * h + 1][j] - mu) * rstd, ghi[j], ehi[j]));
        }
        hreg[h] = pack8(a, b);
      }
    }

    // ===== layer 2: [128]->[64], B operand = hreg (pi-permuted, lane-local),
    // A fragments lane-linear from global (L1-hot), fenced per kb2 =====
    f32x4 acc2[4];
    #pragma unroll
    for (int t = 0; t < 4; ++t)
      acc2[t] = *(const f32x4*)(b2s + t * 16 + q * 4);

    #pragma unroll
    for (int kb2 = 0; kb2 < 4; ++kb2) {
      bf16x8 hb = hreg[kb2];
      #pragma unroll
      for (int t = 0; t < 4; ++t) {
        bf16x8 af = *(const bf16x8*)(w2p + (kb2 * 4 + t) * 512);
        acc2[t] = MFMA16(af, hb, acc2[t]);
      }
      __builtin_amdgcn_sched_barrier(0);   // cap in-flight W2 loads at 4
    }

    // epilogue 2: LN over n=64, GELU, dot with W3, +b3, store
    {
      float s = 0.f, ss = 0.f;
      #pragma unroll
      for (int t = 0; t < 4; ++t)
        #pragma unroll
        for (int j = 0; j < 4; ++j) { float v = acc2[t][j]; s += v; ss += v * v; }
      s  += __shfl_xor(s, 16);  s  += __shfl_xor(s, 32);
      ss += __shfl_xor(ss, 16); ss += __shfl_xor(ss, 32);
      float mu   = s * 0.015625f;
      float var  = ss * 0.015625f - mu * mu;
      var = (var > 0.f) ? var : 0.f;
      float rstd = __builtin_amdgcn_rsqf(var + 1e-5f);

      float dot = 0.f;
      #pragma unroll
      for (int t = 0; t < 4; ++t) {
        f32x4 gv = *(const f32x4*)(g2s + t * 16 + q * 4);
        f32x4 ev = *(const f32x4*)(e2s + t * 16 + q * 4);
        f32x4 wv = *(const f32x4*)(w3s + t * 16 + q * 4);
        #pragma unroll
        for (int j = 0; j < 4; ++j) {
          float zz = __builtin_fmaf((acc2[t][j] - mu) * rstd, gv[j], ev[j]);
          dot = __builtin_fmaf(gelu_fast(zz), wv[j], dot);
        }
      }
      dot += __shfl_xor(dot, 16); dot += __shfl_xor(dot, 32);
      if (q == 0 && r < E) out[r] = dot + b3s[0];
    }
  }
}

extern "C" void kernel_launch(void* const* d_in, const int* in_sizes, int n_in,
                              void* d_out, int out_size, void* d_ws, size_t ws_size,
                              hipStream_t stream) {
  const float* drug = (const float*)d_in[0];
  const float* dis  = (const float*)d_in[1];
  const int*   src  = (const int*)d_in[2];
  const int*   dst  = (const int*)d_in[3];
  const float* W1   = (const float*)d_in[4];
  const float* b1   = (const float*)d_in[5];
  const float* g1   = (const float*)d_in[6];
  const float* be1  = (const float*)d_in[7];
  const float* W2   = (const float*)d_in[8];
  const float* b2   = (const float*)d_in[9];
  const float* g2   = (const float*)d_in[10];
  const float* be2  = (const float*)d_in[11];
  const float* W3   = (const float*)d_in[12];
  const float* b3   = (const float*)d_in[13];
  float* out = (float*)d_out;

  const int E      = in_sizes[2];
  const int ndrug8 = in_sizes[0] / 8;
  const int ndis8  = in_sizes[1] / 8;
  const int ntiles = (E + 127) / 128;      // 128-edge tiles (8 waves x 16 edges)

  short* w1i   = (short*)d_ws;             // 24576 shorts (LDS image, kb 0..5)
  short* w1b   = w1i + 24576;              // 8192 shorts (kb 6,7 lane-linear)
  short* w2L   = w1b + 8192;               // 8192 shorts (W2 lane-linear)
  short* drugb = w2L + 8192;               // bf16 feature tables
  short* disb  = drugb + (size_t)ndrug8 * 8;

  prep_weights<<<dim3(160), dim3(256), 0, stream>>>(W1, W2, w1i, w1b, w2L);
  prep_feats<<<dim3((ndrug8 + 255) / 256), dim3(256), 0, stream>>>(drug, drugb, ndrug8);
  prep_feats<<<dim3((ndis8 + 255) / 256), dim3(256), 0, stream>>>(dis, disb, ndis8);

  int grid = 512;                          // 2 blocks/CU target
  if (ntiles < grid) grid = ntiles;
  mlp_fused<<<dim3(grid), dim3(512), SMEM_BYTES, stream>>>(
      drugb, disb, src, dst, w1i, w1b, w2L,
      b1, g1, be1, b2, g2, be2, W3, b3, out, E, ntiles);
}

// Round 10
// 247.524 us; speedup vs baseline: 1.0557x; 1.0557x over previous
//
#include <hip/hip_runtime.h>
#include <hip/hip_bf16.h>

typedef __attribute__((ext_vector_type(4))) float f32x4;
typedef __attribute__((ext_vector_type(8))) short bf16x8;

#define MFMA16(a, b, c) __builtin_amdgcn_mfma_f32_16x16x32_bf16((a), (b), (c), 0, 0, 0)

// ---- LDS layout (bytes): W1 64K + params ~2.6K = 68128.
// 1024-thr blocks: 2 WGs/CU = 136 KB fits 160 KiB (R2 proved 2-WG co-residency
// at exactly this LDS size with 1024-thr blocks).
#define W1T_OFF 0        // 128 n-rows x 256 k bf16, XOR-swizzled 8-chunks
#define B1_OFF  65536
#define G1_OFF  66048
#define E1_OFF  66560
#define B2_OFF  67072
#define G2_OFF  67328
#define E2_OFF  67584
#define W3_OFF  67840
#define B3_OFF  68096
#define SMEM_BYTES 68128

__device__ __forceinline__ short f2bf(float x) {
  __hip_bfloat16 h = __float2bfloat16(x);
  return __builtin_bit_cast(short, h);
}

__device__ __forceinline__ bf16x8 pack8(f32x4 a, f32x4 b) {
  bf16x8 r;
  r[0] = f2bf(a[0]); r[1] = f2bf(a[1]); r[2] = f2bf(a[2]); r[3] = f2bf(a[3]);
  r[4] = f2bf(b[0]); r[5] = f2bf(b[1]); r[6] = f2bf(b[2]); r[7] = f2bf(b[3]);
  return r;
}

// GELU via logistic CDF fit, log2e folded: z / (1 + exp2(z*(c1 + c2 z^2))).
// |err| <~ 5e-4, under bf16 matmul noise (R4-R9 passed absmax 0.0078).
__device__ __forceinline__ float gelu_fast(float z) {
  float s = z * z;
  float y = z * __builtin_fmaf(-0.10180479f, s, -2.3048496f);
  float t = __builtin_amdgcn_exp2f(y);
  return z * __builtin_amdgcn_rcpf(1.0f + t);
}

// One-time weight prep into workspace:
//   w1i (32768 sh): W1 XOR-swizzled bf16 LDS image (verified R1-R9).
//   w2L (8192 sh): W2 pi-permuted fragments, lane-linear (verified R9):
//        [(kb2*4+t)*512 + lane*8 + e] -> coalesced 1KB/wave loads, L1-hot.
//   forward pi: n -> k = (n>>5)*32 + ((n>>2)&3)*8 + ((n>>4)&1)*4 + (n&3)
__global__ __launch_bounds__(256) void prep_weights(
    const float* __restrict__ W1, const float* __restrict__ W2,
    short* __restrict__ w1i, short* __restrict__ w2L) {
  int idx = blockIdx.x * 256 + threadIdx.x;
  if (idx < 32768) {                       // W1 [k=256][n=128] row-major
    int k = idx >> 7, n = idx & 127;
    w1i[n * 256 + ((((k >> 3) ^ (n & 7)) << 3) | (k & 7))] = f2bf(W1[idx]);
  } else if (idx < 40960) {                // W2 [n=128][n2=64] row-major
    int j = idx - 32768;
    int n = j >> 6, n2 = j & 63;
    int kb2 = n >> 5;
    int qf = (n >> 2) & 3;
    int e = ((n >> 4) & 1) * 4 + (n & 3);
    int t = n2 >> 4, cc2 = n2 & 15;
    w2L[(kb2 * 4 + t) * 512 + (qf * 16 + cc2) * 8 + e] = f2bf(W2[j]);
  }
}

// One-time feature-table conversion f32 -> bf16 (R8-proven: FETCH 307->68 MB).
__global__ __launch_bounds__(256) void prep_feats(
    const float* __restrict__ f, short* __restrict__ o, int n8) {
  int idx = blockIdx.x * 256 + threadIdx.x;
  if (idx < n8) {
    f32x4 a = *(const f32x4*)(f + idx * 8);
    f32x4 b = *(const f32x4*)(f + idx * 8 + 4);
    *(bf16x8*)(o + idx * 8) = pack8(a, b);
  }
}

// Fused gather + (256->128 LN GELU) + (128->64 LN GELU) + (64->1).
// 16 waves/block (1024 thr), 16 edges/wave, 256-edge tiles.
// OCCUPANCY EVIDENCE (R0-R9): 512-thr blocks never co-schedule a 2nd WG/CU
// (~22% = 8 waves/CU regardless of LDS 51-80K, VGPR 72-128); 1024-thr blocks
// reliably give 16-32 waves/CU (R2: 79%, R5: 45%). The only 1024-thr failure
// mode was hipcc's default 64-VGPR budget (spill: WRITE_SIZE 170-990 MB).
// amdgpu_waves_per_eu(2) explicitly sets the allocation target to 2 waves/EU
// (256-reg cap) -- this body needs ~72-104 regs.
// pi-trick: layer-2 B operand = layer-1 accumulators (no H1 round-trip).
__global__ __launch_bounds__(1024) __attribute__((amdgpu_waves_per_eu(2)))
void mlp_fused(
    const short* __restrict__ drugb, const short* __restrict__ disb,
    const int* __restrict__ src, const int* __restrict__ dst,
    const short* __restrict__ w1i, const short* __restrict__ w2L,
    const float* __restrict__ b1, const float* __restrict__ g1, const float* __restrict__ be1,
    const float* __restrict__ b2, const float* __restrict__ g2, const float* __restrict__ be2,
    const float* __restrict__ W3, const float* __restrict__ b3,
    float* __restrict__ out, int E, int ntiles) {
  extern __shared__ char smem[];
  short* w1t = (short*)(smem + W1T_OFF);
  float* b1s = (float*)(smem + B1_OFF);
  float* g1s = (float*)(smem + G1_OFF);
  float* e1s = (float*)(smem + E1_OFF);
  float* b2s = (float*)(smem + B2_OFF);
  float* g2s = (float*)(smem + G2_OFF);
  float* e2s = (float*)(smem + E2_OFF);
  float* w3s = (float*)(smem + W3_OFF);
  float* b3s = (float*)(smem + B3_OFF);

  const int tid  = threadIdx.x;
  const int wave = tid >> 6;    // 0..15
  const int lane = tid & 63;
  const int q    = lane >> 4;   // quad (0..3)
  const int cc   = lane & 15;   // col-within-tile = edge slot

  // ---- one-time: linear copy of pre-swizzled 64KB W1 image into LDS ----
  #pragma unroll
  for (int o = 0; o < 4; ++o) {
    int s = (tid + o * 1024) * 8;          // shorts; 16B/thread/pass, 4 passes
    *(bf16x8*)(w1t + s) = *(const bf16x8*)(w1i + s);
  }
  if (tid < 128) { b1s[tid] = b1[tid]; g1s[tid] = g1[tid]; e1s[tid] = be1[tid]; }
  else if (tid < 192) { int j = tid - 128; b2s[j] = b2[j]; g2s[j] = g2[j]; e2s[j] = be2[j]; w3s[j] = W3[j]; }
  if (tid == 256) b3s[0] = b3[0];
  __syncthreads();

  // per-lane W2 fragment base (lane-linear global, coalesced, L1-hot)
  const short* w2p = w2L + (lane << 3);

  // ---- persistent loop over 256-edge tiles; waves free-run (no per-tile sync) ----
  for (int tile = blockIdx.x; tile < ntiles; tile += gridDim.x) {
    const int r  = tile * 256 + wave * 16 + cc;       // this lane's edge row
    const int rc = (r < E) ? r : (E - 1);             // clamp reads, guard writes
    const short* pd = drugb + (size_t)src[rc] * 128 + q * 8;
    const short* pq = disb  + (size_t)dst[rc] * 128 + q * 8;

    // ===== layer 1: [256]->[128], K=256, acc init = b1 (bias folded) =====
    f32x4 acc1[8];
    #pragma unroll
    for (int nt = 0; nt < 8; ++nt)
      acc1[nt] = *(const f32x4*)(b1s + nt * 16 + q * 4);

    bf16x8 u = *(const bf16x8*)pd;         // prefetch kb=0
    #pragma unroll 1
    for (int kb = 0; kb < 8; ++kb) {
      bf16x8 bfr = u;
      if (kb < 7) {                        // issue kb+1 load before kb's MFMAs
        const short* pn = (kb < 3) ? (pd + (kb + 1) * 32) : (pq + (kb - 3) * 32);
        u = *(const bf16x8*)pn;
      }
      const char* abase = (const char*)w1t + cc * 512 + ((((kb * 4 + q) ^ (cc & 7))) << 4);
      #pragma unroll
      for (int nt = 0; nt < 8; ++nt) {
        bf16x8 af = *(const bf16x8*)(abase + nt * 8192);
        acc1[nt] = MFMA16(af, bfr, acc1[nt]);
      }
    }

    // epilogue 1: LN over n=128, GELU, pack to bf16 hreg (acc1 dies here)
    bf16x8 hreg[4];
    {
      float s = 0.f, ss = 0.f;
      #pragma unroll
      for (int nt = 0; nt < 8; ++nt)
        #pragma unroll
        for (int j = 0; j < 4; ++j) { float v = acc1[nt][j]; s += v; ss += v * v; }
      s  += __shfl_xor(s, 16);  s  += __shfl_xor(s, 32);
      ss += __shfl_xor(ss, 16); ss += __shfl_xor(ss, 32);
      float mu   = s * 0.0078125f;
      float var  = ss * 0.0078125f - mu * mu;
      var = (var > 0.f) ? var : 0.f;
      float rstd = __builtin_amdgcn_rsqf(var + 1e-5f);

      #pragma unroll
      for (int h = 0; h < 4; ++h) {
        f32x4 glo = *(const f32x4*)(g1s + (2 * h) * 16 + q * 4);
        f32x4 elo = *(const f32x4*)(e1s + (2 * h) * 16 + q * 4);
        f32x4 ghi = *(const f32x4*)(g1s + (2 * h + 1) * 16 + q * 4);
        f32x4 ehi = *(const f32x4*)(e1s + (2 * h + 1) * 16 + q * 4);
        f32x4 a, b;
        #pragma unroll
        for (int j = 0; j < 4; ++j) {
          a[j] = gelu_fast(__builtin_fmaf((acc1[2 * h][j] - mu) * rstd, glo[j], elo[j]));
          b[j] = gelu_fast(__builtin_fmaf((acc1[2 * h + 1][j] - mu) * rstd, ghi[j], ehi[j]));
        }
        hreg[h] = pack8(a, b);
      }
    }

    // ===== layer 2: [128]->[64], B operand = hreg (pi-permuted, lane-local),
    // A fragments lane-linear from global (L1-hot), fenced per kb2 =====
    f32x4 acc2[4];
    #pragma unroll
    for (int t = 0; t < 4; ++t)
      acc2[t] = *(const f32x4*)(b2s + t * 16 + q * 4);

    #pragma unroll
    for (int kb2 = 0; kb2 < 4; ++kb2) {
      bf16x8 hb = hreg[kb2];
      #pragma unroll
      for (int t = 0; t < 4; ++t) {
        bf16x8 af = *(const bf16x8*)(w2p + (kb2 * 4 + t) * 512);
        acc2[t] = MFMA16(af, hb, acc2[t]);
      }
      __builtin_amdgcn_sched_barrier(0);   // cap in-flight W2 loads at 4 (16 regs)
    }

    // epilogue 2: LN over n=64, GELU, dot with W3, +b3, store
    {
      float s = 0.f, ss = 0.f;
      #pragma unroll
      for (int t = 0; t < 4; ++t)
        #pragma unroll
        for (int j = 0; j < 4; ++j) { float v = acc2[t][j]; s += v; ss += v * v; }
      s  += __shfl_xor(s, 16);  s  += __shfl_xor(s, 32);
      ss += __shfl_xor(ss, 16); ss += __shfl_xor(ss, 32);
      float mu   = s * 0.015625f;
      float var  = ss * 0.015625f - mu * mu;
      var = (var > 0.f) ? var : 0.f;
      float rstd = __builtin_amdgcn_rsqf(var + 1e-5f);

      float dot = 0.f;
      #pragma unroll
      for (int t = 0; t < 4; ++t) {
        f32x4 gv = *(const f32x4*)(g2s + t * 16 + q * 4);
        f32x4 ev = *(const f32x4*)(e2s + t * 16 + q * 4);
        f32x4 wv = *(const f32x4*)(w3s + t * 16 + q * 4);
        #pragma unroll
        for (int j = 0; j < 4; ++j) {
          float zz = __builtin_fmaf((acc2[t][j] - mu) * rstd, gv[j], ev[j]);
          dot = __builtin_fmaf(gelu_fast(zz), wv[j], dot);
        }
      }
      dot += __shfl_xor(dot, 16); dot += __shfl_xor(dot, 32);
      if (q == 0 && r < E) out[r] = dot + b3s[0];
    }
  }
}

extern "C" void kernel_launch(void* const* d_in, const int* in_sizes, int n_in,
                              void* d_out, int out_size, void* d_ws, size_t ws_size,
                              hipStream_t stream) {
  const float* drug = (const float*)d_in[0];
  const float* dis  = (const float*)d_in[1];
  const int*   src  = (const int*)d_in[2];
  const int*   dst  = (const int*)d_in[3];
  const float* W1   = (const float*)d_in[4];
  const float* b1   = (const float*)d_in[5];
  const float* g1   = (const float*)d_in[6];
  const float* be1  = (const float*)d_in[7];
  const float* W2   = (const float*)d_in[8];
  const float* b2   = (const float*)d_in[9];
  const float* g2   = (const float*)d_in[10];
  const float* be2  = (const float*)d_in[11];
  const float* W3   = (const float*)d_in[12];
  const float* b3   = (const float*)d_in[13];
  float* out = (float*)d_out;

  const int E      = in_sizes[2];
  const int ndrug8 = in_sizes[0] / 8;
  const int ndis8  = in_sizes[1] / 8;
  const int ntiles = (E + 255) / 256;      // 256-edge tiles (16 waves x 16 edges)

  short* w1i   = (short*)d_ws;             // 32768 shorts (full LDS image)
  short* w2L   = w1i + 32768;              // 8192 shorts (W2 lane-linear)
  short* drugb = w2L + 8192;               // bf16 feature tables
  short* disb  = drugb + (size_t)ndrug8 * 8;

  (void)hipFuncSetAttribute((const void*)mlp_fused,
                            hipFuncAttributeMaxDynamicSharedMemorySize, SMEM_BYTES);

  prep_weights<<<dim3(160), dim3(256), 0, stream>>>(W1, W2, w1i, w2L);
  prep_feats<<<dim3((ndrug8 + 255) / 256), dim3(256), 0, stream>>>(drug, drugb, ndrug8);
  prep_feats<<<dim3((ndis8 + 255) / 256), dim3(256), 0, stream>>>(dis, disb, ndis8);

  int grid = 512;                          // 2 WGs/CU upside (R2 precedent)
  if (ntiles < grid) grid = ntiles;
  mlp_fused<<<dim3(grid), dim3(1024), SMEM_BYTES, stream>>>(
      drugb, disb, src, dst, w1i, w2L,
      b1, g1, be1, b2, g2, be2, W3, b3, out, E, ntiles);
}